// Round 9
// baseline (226.339 us; speedup 1.0000x reference)
//
#include <hip/hip_runtime.h>

#define HH 16
#define DKK 64
#define SS 2048
#define BB 2
#define DD 1024

typedef __attribute__((ext_vector_type(4))) float f32x4;
typedef __attribute__((ext_vector_type(8))) short bf16x8;
typedef __attribute__((ext_vector_type(4))) short s16x4;
typedef __attribute__((ext_vector_type(2))) int i32x2;

// s_waitcnt immediates: vmcnt[3:0]|expcnt[6:4]|lgkmcnt[11:8]|vmcnt[5:4]<<14
#define WAITCNT_VM8 0xF78  // vmcnt(8), ignore exp/lgkm
#define WAITCNT_VM0 0xF70  // vmcnt(0)

__device__ __forceinline__ short bf16b(float f) {
    union { float f; unsigned u; } x; x.f = f;
    unsigned r = (x.u + 0x7fffu + ((x.u >> 16) & 1u)) >> 16;
    return (short)r;
}

__device__ __forceinline__ unsigned f2u(float f) {
    union { float f; unsigned u; } x; x.f = f;
    return x.u;
}

__device__ __forceinline__ f32x4 mfma16(bf16x8 a, bf16x8 b, f32x4 c) {
    return __builtin_amdgcn_mfma_f32_16x16x32_bf16(a, b, c, 0, 0, 0);
}

__device__ __forceinline__ void lds16(const short* g, short* l) {
    __builtin_amdgcn_global_load_lds(
        (const __attribute__((address_space(1))) void*)g,
        (__attribute__((address_space(3))) void*)l, 16, 0, 0);
}

// ---------------- merged prologue: cast + transpose + bias in ONE launch ----------------
// blocks [0,4096): hs fp32->bf16; [4096,8192): weight transpose; [8192,8448): bias.
__global__ __launch_bounds__(256) void prep(
    const float* __restrict__ hs,
    const float* __restrict__ W0, const float* __restrict__ W1,
    const float* __restrict__ W2, const float* __restrict__ W3,
    const float* __restrict__ rb,
    short* __restrict__ hsb,
    short* __restrict__ T0, short* __restrict__ T1,
    short* __restrict__ T2, short* __restrict__ T3,
    float* __restrict__ tab) {
    __shared__ short tile[32][33];
    int blk = blockIdx.x, tid = threadIdx.x;
    if (blk < 4096) {
        int i = (blk * 256 + tid) * 4;
        f32x4 v = *(const f32x4*)(hs + i);
        s16x4 o;
        o.x = bf16b(v.x); o.y = bf16b(v.y); o.z = bf16b(v.z); o.w = bf16b(v.w);
        *(s16x4*)(hsb + i) = o;
    } else if (blk < 8192) {
        int t = blk - 4096;
        int z = t >> 10, r = t & 1023;
        int bx = r & 31, by = r >> 5;
        const float* W; short* T;
        switch (z) {
            case 0: W = W0; T = T0; break;
            case 1: W = W1; T = T1; break;
            case 2: W = W2; T = T2; break;
            default: W = W3; T = T3; break;
        }
        int n0 = bx * 32, k0 = by * 32;
        int tx = tid & 31, ty = (tid >> 5) * 4;
#pragma unroll
        for (int i = 0; i < 4; i++)
            tile[ty + i][tx] = bf16b(W[(k0 + ty + i) * DD + n0 + tx]);
        __syncthreads();
#pragma unroll
        for (int i = 0; i < 4; i++)
            T[(n0 + ty + i) * DD + k0 + tx] = tile[tx][ty + i];
    } else {
        int idx = (blk - 8192) * 256 + tid;
        if (idx < HH * 4095) {
            int h = idx / 4095, d = idx % 4095;
            int rel = d - 2047; // k - q
            int bucket = (rel > 0) ? 16 : 0;
            unsigned rr = (rel < 0) ? (unsigned)(-rel) : (unsigned)rel;
            int add;
            if (rr < 8) add = (int)rr;
            else {
                int e = 31 - __clz(rr);
                unsigned long long r2 = (unsigned long long)rr * (unsigned long long)rr;
                int f = 2 * e + ((r2 >= (2ull << (2 * e))) ? 1 : 0);
                add = 8 + (f - 6);
                if (add > 15) add = 15;
            }
            bucket += add;
            tab[h * 4095 + d] = rb[bucket * HH + h] * 1.44269504f;
        }
    }
}

// ---------------- barrier-free GEMM: C = A[M][1024] * Bt[N][1024]^T ----------------
// 128-thread blocks (2 waves), 128x64 tile; wave owns a PRIVATE 64-row A strip and
// a private (duplicated) copy of the 64-row B tile in its own LDS region -> no
// cross-wave sharing -> ZERO __syncthreads. Per iter: issue 8 DMAs for k+32 into
// buf^1, s_waitcnt vmcnt(8) (ordered semantics: drains exactly the previous iter's
// 8 — m135), fence, 16 MFMAs on buf cur. This removes the vmcnt(0)-before-barrier
// drain that pinned the m97-structure GEMMs at MfmaUtil ~12% (measured r7).
// EPI 0: scatter Q/K [B][H][S][DK] bf16, V^T [B][H][DK][S]; EPI 1: fp32 [M][1024].
template <int EPI>
__global__ __launch_bounds__(128) void gemm_bf(
    const short* __restrict__ A, const short* __restrict__ Bt,
    short* __restrict__ Cq, short* __restrict__ Ck, short* __restrict__ Cvt,
    float* __restrict__ Cout) {
    const int K = 1024;
    __shared__ short As[2][2][2048]; // [wave][buf] 64 rows x 32 k
    __shared__ short Bs[2][2][2048];
    int tid = threadIdx.x;
    int wave = tid >> 6, lane = tid & 63;
    int quad = lane >> 4, l16 = lane & 15;
    int m0 = blockIdx.y * 128 + wave * 64;
    int n0 = blockIdx.x * 64;

    int rA = lane >> 2, cg = lane & 3; // call c covers rows c*16+rA, col-granule cg
    const short* Ag[4];
    const short* Bg[4];
#pragma unroll
    for (int c = 0; c < 4; c++) {
        Ag[c] = A + (size_t)(m0 + c * 16 + rA) * K + cg * 8;
        Bg[c] = Bt + (size_t)(n0 + c * 16 + rA) * K + cg * 8;
    }
    short* Aw[2] = {&As[wave][0][0], &As[wave][1][0]};
    short* Bw[2] = {&Bs[wave][0][0], &Bs[wave][1][0]};

    f32x4 acc[4][4];
#pragma unroll
    for (int i = 0; i < 4; i++)
#pragma unroll
        for (int j = 0; j < 4; j++) acc[i][j] = (f32x4){0.f, 0.f, 0.f, 0.f};

    // prologue: stage k=0 into buf 0 (8 DMAs)
#pragma unroll
    for (int c = 0; c < 4; c++) {
        lds16(Ag[c], Aw[0] + c * 512);
        lds16(Bg[c], Bw[0] + c * 512);
    }

    for (int k0 = 0; k0 < K; k0 += 32) {
        int cur = (k0 >> 5) & 1, nxt = cur ^ 1;
        int kn = (k0 + 32) & (K - 1); // wraps on last iter (drained, discarded)
#pragma unroll
        for (int c = 0; c < 4; c++) {
            lds16(Ag[c] + kn, Aw[nxt] + c * 512);
            lds16(Bg[c] + kn, Bw[nxt] + c * 512);
        }
        __builtin_amdgcn_s_waitcnt(WAITCNT_VM8); // prev iter's 8 DMAs landed
        __asm__ __volatile__("" ::: "memory");   // no LDS-read hoisting above

        bf16x8 af[4], bfr[4];
#pragma unroll
        for (int t = 0; t < 4; t++) {
            af[t] = *(const bf16x8*)(Aw[cur] + (t * 16 + l16) * 32 + quad * 8);
            bfr[t] = *(const bf16x8*)(Bw[cur] + (t * 16 + l16) * 32 + quad * 8);
        }
#pragma unroll
        for (int mt = 0; mt < 4; mt++)
#pragma unroll
            for (int nt = 0; nt < 4; nt++)
                acc[mt][nt] = mfma16(af[mt], bfr[nt], acc[mt][nt]);
    }
    __builtin_amdgcn_s_waitcnt(WAITCNT_VM0); // wrapped DMAs land before retirement

#pragma unroll
    for (int mt = 0; mt < 4; mt++) {
#pragma unroll
        for (int nt = 0; nt < 4; nt++) {
#pragma unroll
            for (int r = 0; r < 4; r++) {
                int gm = m0 + mt * 16 + quad * 4 + r;
                int gn = n0 + nt * 16 + l16;
                float v = acc[mt][nt][r];
                if (EPI == 1) {
                    Cout[(size_t)gm * 1024 + gn] = v;
                } else {
                    int b = gm >> 11, s = gm & 2047;
                    int which = gn >> 10; // uniform per tile (64 | 1024)
                    int h = (gn >> 6) & 15, dk = gn & 63;
                    short bv = bf16b(v);
                    if (which == 0)
                        Cq[(((size_t)(b * HH + h)) * SS + s) * DKK + dk] = bv;
                    else if (which == 1)
                        Ck[(((size_t)(b * HH + h)) * SS + s) * DKK + dk] = bv;
                    else
                        Cvt[(((size_t)(b * HH + h)) * DKK + dk) * SS + s] = bv;
                }
            }
        }
    }
}

// ---------------- attention: DMA double-buffered, strip-interleaved ----------------
// (round-5 version + final vmcnt(0) drain — measured 60-62 µs, MfmaUtil 25%.)
__global__ __launch_bounds__(256, 2) void attn(
    const short* __restrict__ Q, const short* __restrict__ Kmat,
    const short* __restrict__ Vt, const float* __restrict__ btab,
    short* __restrict__ O) {
    __shared__ short Ks[2][64 * 64];
    __shared__ short Vs[2][64 * 64];
    __shared__ float bias_s[2176];
    __shared__ short P_s[4][2][16 * 64];

    int tid = threadIdx.x;
    int wave = tid >> 6, lane = tid & 63;
    int quad = lane >> 4, l16 = lane & 15;
    int bh = blockIdx.x;
    int h = bh & 15, b = bh >> 4;
    int q0b = blockIdx.y * 128;
    int q0w = q0b + wave * 32;

    const short* Qb = Q + (size_t)bh * SS * DKK;
    const short* Kb = Kmat + (size_t)bh * SS * DKK;
    const short* Vb = Vt + (size_t)bh * DKK * SS;
    const float* bt = btab + h * 4095;

    int woff = 1920 - q0b;
    for (int i = tid; i < 2176; i += 256) {
        int gi = woff + i;
        bias_s[i] = bt[gi > 4094 ? 4094 : gi];
    }
    float blo = bt[2047 - 128];
    float bhi = bt[2047 + 128];

    int kro = tid >> 3;
    int gk = (tid & 7) ^ (kro & 7);
    const short* Kg0 = Kb + (size_t)kro * DKK + gk * 8;
    const short* Kg1 = Kb + (size_t)(kro + 32) * DKK + gk * 8;
    const short* Vg0 = Vb + (size_t)kro * SS + gk * 8;
    const short* Vg1 = Vb + (size_t)(kro + 32) * SS + gk * 8;

    bf16x8 qf[2][2];
#pragma unroll
    for (int qs = 0; qs < 2; qs++) {
        qf[qs][0] = *(const bf16x8*)(Qb + (q0w + qs * 16 + l16) * DKK + quad * 8);
        qf[qs][1] = *(const bf16x8*)(Qb + (q0w + qs * 16 + l16) * DKK + 32 + quad * 8);
    }

    f32x4 o[2][4];
#pragma unroll
    for (int qs = 0; qs < 2; qs++)
#pragma unroll
        for (int i = 0; i < 4; i++) o[qs][i] = (f32x4){0.f, 0.f, 0.f, 0.f};
    f32x4 lacc[2];
    lacc[0] = (f32x4){0.f, 0.f, 0.f, 0.f};
    lacc[1] = (f32x4){0.f, 0.f, 0.f, 0.f};

    bf16x8 onesf;
    short onev = (l16 == 0) ? (short)0x3F80 : (short)0;
#pragma unroll
    for (int i = 0; i < 8; i++) onesf[i] = onev;

    short* Pw = &P_s[wave][0][0];
    int gxor = l16 & 7;
    int ghalf = quad >> 1;
    int wbase = l16 * 64 + (quad & 1) * 4;
    int ra0 = l16 * 64 + ((quad ^ gxor) * 8);
    int ra1 = l16 * 64 + (((4 + quad) ^ gxor) * 8);
    int bidx = 127 + quad * 4 - wave * 32 - l16;
    int sl0 = (quad ^ gxor) * 8;
    int sl1 = ((4 + quad) ^ gxor) * 8;

    lds16(Kg0, &Ks[0][wave * 512]);
    lds16(Kg1, &Ks[0][2048 + wave * 512]);
    lds16(Vg0, &Vs[0][wave * 512]);
    lds16(Vg1, &Vs[0][2048 + wave * 512]);

    int cur = 0;
    for (int kc = 0; kc < SS; kc += 64) {
        __syncthreads();
        int kn = (kc + 64) & (SS - 1);
        int nxt = cur ^ 1;
        lds16(Kg0 + (size_t)kn * DKK, &Ks[nxt][wave * 512]);
        lds16(Kg1 + (size_t)kn * DKK, &Ks[nxt][2048 + wave * 512]);
        lds16(Vg0 + kn, &Vs[nxt][wave * 512]);
        lds16(Vg1 + kn, &Vs[nxt][2048 + wave * 512]);

        float breg[2][16];
#pragma unroll
        for (int qs = 0; qs < 2; qs++) {
            int q0s = q0w + qs * 16;
            if (kc > q0s - 191 && kc < q0s + 143) {
#pragma unroll
                for (int kt = 0; kt < 4; kt++)
#pragma unroll
                    for (int r = 0; r < 4; r++)
                        breg[qs][kt * 4 + r] =
                            bias_s[bidx + kc + kt * 16 + r - qs * 16];
            } else {
                float bc = (kc <= q0s - 191) ? blo : bhi;
#pragma unroll
                for (int i = 0; i < 16; i++) breg[qs][i] = bc;
            }
        }

        const short* Ksc = &Ks[cur][0];
        const short* Vsc = &Vs[cur][0];

        f32x4 s[2][4];
#pragma unroll
        for (int kt = 0; kt < 4; kt++) {
            int row = (kt * 16 + l16) * 64;
            bf16x8 kf0 = *(const bf16x8*)(Ksc + row + sl0);
            bf16x8 kf1 = *(const bf16x8*)(Ksc + row + sl1);
            s[0][kt] = mfma16(kf0, qf[0][0], (f32x4){0.f, 0.f, 0.f, 0.f});
            s[0][kt] = mfma16(kf1, qf[0][1], s[0][kt]);
            s[1][kt] = mfma16(kf0, qf[1][0], (f32x4){0.f, 0.f, 0.f, 0.f});
            s[1][kt] = mfma16(kf1, qf[1][1], s[1][kt]);
        }
        bf16x8 vf[4][2];
#pragma unroll
        for (int nt = 0; nt < 4; nt++) {
            int row = (nt * 16 + l16) * 64;
            vf[nt][0] = *(const bf16x8*)(Vsc + row + sl0);
            vf[nt][1] = *(const bf16x8*)(Vsc + row + sl1);
        }

#pragma unroll
        for (int qs = 0; qs < 2; qs++) {
#pragma unroll
            for (int kt = 0; kt < 4; kt++) {
                unsigned u[4];
#pragma unroll
                for (int r = 0; r < 4; r++) {
                    float p = __builtin_amdgcn_exp2f(
                        fmaf(s[qs][kt][r], 1.44269504f, breg[qs][kt * 4 + r]));
                    u[r] = f2u(p) + 0x8000u;
                }
                unsigned d0 = __builtin_amdgcn_perm(u[1], u[0], 0x07060302u);
                unsigned d1 = __builtin_amdgcn_perm(u[3], u[2], 0x07060302u);
                int g = (kt * 2 + ghalf) ^ gxor;
                *(i32x2*)(Pw + qs * 1024 + wbase + g * 8) = (i32x2){(int)d0, (int)d1};
            }
        }
        __asm__ __volatile__("" ::: "memory");
#pragma unroll
        for (int qs = 0; qs < 2; qs++) {
            bf16x8 pf0 = *(const bf16x8*)(Pw + qs * 1024 + ra0);
            bf16x8 pf1 = *(const bf16x8*)(Pw + qs * 1024 + ra1);
            lacc[qs] = mfma16(pf0, onesf, lacc[qs]);
            lacc[qs] = mfma16(pf1, onesf, lacc[qs]);
#pragma unroll
            for (int nt = 0; nt < 4; nt++) {
                o[qs][nt] = mfma16(pf0, vf[nt][0], o[qs][nt]);
                o[qs][nt] = mfma16(pf1, vf[nt][1], o[qs][nt]);
            }
        }
        __asm__ __volatile__("" ::: "memory");
        cur ^= 1;
    }
    __builtin_amdgcn_s_waitcnt(WAITCNT_VM0); // wrapped DMAs land before retirement

#pragma unroll
    for (int qs = 0; qs < 2; qs++) {
        float inv[4];
#pragma unroll
        for (int r = 0; r < 4; r++) {
            float l = __shfl(lacc[qs][r], lane & 48);
            inv[r] = 1.f / l;
        }
#pragma unroll
        for (int nt = 0; nt < 4; nt++)
#pragma unroll
            for (int r = 0; r < 4; r++) {
                int qrow = q0w + qs * 16 + quad * 4 + r;
                int dk = nt * 16 + l16;
                O[((size_t)(b * SS + qrow)) * (HH * DKK) + h * DKK + dk] =
                    bf16b(o[qs][nt][r] * inv[r]);
            }
    }
}

extern "C" void kernel_launch(void* const* d_in, const int* in_sizes, int n_in,
                              void* d_out, int out_size, void* d_ws, size_t ws_size,
                              hipStream_t stream) {
    const float* hs = (const float*)d_in[0];
    const float* Wq = (const float*)d_in[1];
    const float* Wk = (const float*)d_in[2];
    const float* Wv = (const float*)d_in[3];
    const float* Wo = (const float*)d_in[4];
    const float* rb = (const float*)d_in[5];
    float* out = (float*)d_out;

    char* ws = (char*)d_ws;
    size_t off = 0;
    auto alloc = [&](size_t bytes) -> void* {
        void* p = (void*)(ws + off);
        off += (bytes + 255) & ~(size_t)255;
        return p;
    };
    const size_t M = (size_t)BB * SS; // 4096
    short* hsb = (short*)alloc(M * DD * 2);
    // WqT/WkT/WvT MUST stay contiguous (2MB each, 256-aligned -> no padding):
    // gemm_bf<0> reads them as one [3072][1024] matrix.
    short* WqT = (short*)alloc((size_t)DD * DD * 2);
    short* WkT = (short*)alloc((size_t)DD * DD * 2);
    short* WvT = (short*)alloc((size_t)DD * DD * 2);
    short* WoT = (short*)alloc((size_t)DD * DD * 2);
    short* Qb  = (short*)alloc(M * DD * 2);
    short* Kb  = (short*)alloc(M * DD * 2);
    short* VTb = (short*)alloc(M * DD * 2);
    short* Ab  = (short*)alloc(M * DD * 2);
    float* btab = (float*)alloc((size_t)HH * 4095 * 4);

    prep<<<8448, 256, 0, stream>>>(hs, Wq, Wk, Wv, Wo, rb,
                                   hsb, WqT, WkT, WvT, WoT, btab);
    gemm_bf<0><<<dim3(48, 32), 128, 0, stream>>>(hsb, WqT, Qb, Kb, VTb, nullptr);
    attn<<<dim3(32, 16), 256, 0, stream>>>(Qb, Kb, VTb, btab, Ab);
    gemm_bf<1><<<dim3(16, 32), 128, 0, stream>>>(Ab, WoT, nullptr, nullptr, nullptr, out);
}

// Round 10
// 192.605 us; speedup vs baseline: 1.1751x; 1.1751x over previous
//
#include <hip/hip_runtime.h>

#define HH 16
#define DKK 64
#define SS 2048
#define BB 2
#define DD 1024

typedef __attribute__((ext_vector_type(4))) float f32x4;
typedef __attribute__((ext_vector_type(8))) short bf16x8;
typedef __attribute__((ext_vector_type(4))) short s16x4;
typedef __attribute__((ext_vector_type(2))) int i32x2;

#define WAITCNT_VM0 0xF70  // vmcnt(0), ignore exp/lgkm

__device__ __forceinline__ short bf16b(float f) {
    union { float f; unsigned u; } x; x.f = f;
    unsigned r = (x.u + 0x7fffu + ((x.u >> 16) & 1u)) >> 16;
    return (short)r;
}

__device__ __forceinline__ unsigned f2u(float f) {
    union { float f; unsigned u; } x; x.f = f;
    return x.u;
}

__device__ __forceinline__ f32x4 mfma16(bf16x8 a, bf16x8 b, f32x4 c) {
    return __builtin_amdgcn_mfma_f32_16x16x32_bf16(a, b, c, 0, 0, 0);
}

__device__ __forceinline__ void lds16(const short* g, short* l) {
    __builtin_amdgcn_global_load_lds(
        (const __attribute__((address_space(1))) void*)g,
        (__attribute__((address_space(3))) void*)l, 16, 0, 0);
}

// ---------------- merged prologue: cast + transpose + bias in ONE launch ----------------
// blocks [0,4096): hs fp32->bf16; [4096,8192): weight transpose; [8192,8448): bias.
// (verified r9 — all three stages fill the machine concurrently)
__global__ __launch_bounds__(256) void prep(
    const float* __restrict__ hs,
    const float* __restrict__ W0, const float* __restrict__ W1,
    const float* __restrict__ W2, const float* __restrict__ W3,
    const float* __restrict__ rb,
    short* __restrict__ hsb,
    short* __restrict__ T0, short* __restrict__ T1,
    short* __restrict__ T2, short* __restrict__ T3,
    float* __restrict__ tab) {
    __shared__ short tile[32][33];
    int blk = blockIdx.x, tid = threadIdx.x;
    if (blk < 4096) {
        int i = (blk * 256 + tid) * 4;
        f32x4 v = *(const f32x4*)(hs + i);
        s16x4 o;
        o.x = bf16b(v.x); o.y = bf16b(v.y); o.z = bf16b(v.z); o.w = bf16b(v.w);
        *(s16x4*)(hsb + i) = o;
    } else if (blk < 8192) {
        int t = blk - 4096;
        int z = t >> 10, r = t & 1023;
        int bx = r & 31, by = r >> 5;
        const float* W; short* T;
        switch (z) {
            case 0: W = W0; T = T0; break;
            case 1: W = W1; T = T1; break;
            case 2: W = W2; T = T2; break;
            default: W = W3; T = T3; break;
        }
        int n0 = bx * 32, k0 = by * 32;
        int tx = tid & 31, ty = (tid >> 5) * 4;
#pragma unroll
        for (int i = 0; i < 4; i++)
            tile[ty + i][tx] = bf16b(W[(k0 + ty + i) * DD + n0 + tx]);
        __syncthreads();
#pragma unroll
        for (int i = 0; i < 4; i++)
            T[(n0 + ty + i) * DD + k0 + tx] = tile[tx][ty + i];
    } else {
        int idx = (blk - 8192) * 256 + tid;
        if (idx < HH * 4095) {
            int h = idx / 4095, d = idx % 4095;
            int rel = d - 2047; // k - q
            int bucket = (rel > 0) ? 16 : 0;
            unsigned rr = (rel < 0) ? (unsigned)(-rel) : (unsigned)rel;
            int add;
            if (rr < 8) add = (int)rr;
            else {
                int e = 31 - __clz(rr);
                unsigned long long r2 = (unsigned long long)rr * (unsigned long long)rr;
                int f = 2 * e + ((r2 >= (2ull << (2 * e))) ? 1 : 0);
                add = 8 + (f - 6);
                if (add > 15) add = 15;
            }
            bucket += add;
            tab[h * 4095 + d] = rb[bucket * HH + h] * 1.44269504f;
        }
    }
}

// ---------------- fused QKV GEMM (r5-exact): C = A[4096][1024] * Wt[3072][1024]^T ----
// m97 2-barrier loop, grid (24 n, 32 m) — measured-best total config.
// Epilogue scatters Q/K -> [B][H][S][DK] bf16, V -> [B][H][DK][S] bf16.
__global__ __launch_bounds__(256) void gemm_qkv(
    const short* __restrict__ A, const short* __restrict__ Wt,
    short* __restrict__ Cq, short* __restrict__ Ck, short* __restrict__ Cvt) {
    const int K = 1024;
    __shared__ short As[128 * 32];
    __shared__ short Bs[128 * 32];
    int tid = threadIdx.x;
    int wave = tid >> 6, lane = tid & 63;
    int quad = lane >> 4, l16 = lane & 15;
    int m0 = blockIdx.y * 128, n0 = blockIdx.x * 128;

    int wm = (wave & 1) * 64, wn = (wave >> 1) * 64;
    int r0 = tid >> 2, c0 = (tid & 3) * 8;

    f32x4 acc[4][4];
#pragma unroll
    for (int i = 0; i < 4; i++)
#pragma unroll
        for (int j = 0; j < 4; j++) acc[i][j] = (f32x4){0.f, 0.f, 0.f, 0.f};

    for (int k0 = 0; k0 < K; k0 += 32) {
        __syncthreads();
        lds16(A + (size_t)(m0 + r0) * K + k0 + c0, As + wave * 512);
        lds16(A + (size_t)(m0 + 64 + r0) * K + k0 + c0, As + 2048 + wave * 512);
        lds16(Wt + (size_t)(n0 + r0) * K + k0 + c0, Bs + wave * 512);
        lds16(Wt + (size_t)(n0 + 64 + r0) * K + k0 + c0, Bs + 2048 + wave * 512);
        __syncthreads();
        bf16x8 af[4], bfr[4];
#pragma unroll
        for (int t = 0; t < 4; t++) {
            af[t] = *(const bf16x8*)(As + (wm + t * 16 + l16) * 32 + quad * 8);
            bfr[t] = *(const bf16x8*)(Bs + (wn + t * 16 + l16) * 32 + quad * 8);
        }
#pragma unroll
        for (int mt = 0; mt < 4; mt++)
#pragma unroll
            for (int nt = 0; nt < 4; nt++)
                acc[mt][nt] = mfma16(af[mt], bfr[nt], acc[mt][nt]);
    }

#pragma unroll
    for (int mt = 0; mt < 4; mt++) {
#pragma unroll
        for (int nt = 0; nt < 4; nt++) {
#pragma unroll
            for (int r = 0; r < 4; r++) {
                int gm = m0 + wm + mt * 16 + quad * 4 + r;
                int gn = n0 + wn + nt * 16 + l16;
                int b = gm >> 11, s = gm & 2047;
                int which = gn >> 10;       // wave-uniform per nt
                int h = (gn >> 6) & 15, dk = gn & 63;
                short bv = bf16b(acc[mt][nt][r]);
                if (which == 0)
                    Cq[(((size_t)(b * HH + h)) * SS + s) * DKK + dk] = bv;
                else if (which == 1)
                    Ck[(((size_t)(b * HH + h)) * SS + s) * DKK + dk] = bv;
                else
                    Cvt[(((size_t)(b * HH + h)) * DKK + dk) * SS + s] = bv;
            }
        }
    }
}

// ---------------- output projection (r5-exact): C[4096][1024] fp32 = A * WoT^T ------
__global__ __launch_bounds__(256) void gemm_out(
    const short* __restrict__ A, const short* __restrict__ Wt,
    float* __restrict__ Cout) {
    const int K = 1024, N = 1024;
    __shared__ short As[64 * 32];
    __shared__ short Bs[128 * 32];
    int tid = threadIdx.x;
    int wave = tid >> 6, lane = tid & 63;
    int quad = lane >> 4, l16 = lane & 15;
    int m0 = blockIdx.y * 64, n0 = blockIdx.x * 128;

    int wm = (wave & 1) * 32, wn = (wave >> 1) * 64;
    int r0 = tid >> 2, c0 = (tid & 3) * 8;

    f32x4 acc[2][4];
#pragma unroll
    for (int i = 0; i < 2; i++)
#pragma unroll
        for (int j = 0; j < 4; j++) acc[i][j] = (f32x4){0.f, 0.f, 0.f, 0.f};

    for (int k0 = 0; k0 < K; k0 += 32) {
        __syncthreads();
        lds16(A + (size_t)(m0 + r0) * K + k0 + c0, As + wave * 512);
        lds16(Wt + (size_t)(n0 + r0) * K + k0 + c0, Bs + wave * 512);
        lds16(Wt + (size_t)(n0 + 64 + r0) * K + k0 + c0, Bs + 2048 + wave * 512);
        __syncthreads();
        bf16x8 af[2], bfr[4];
#pragma unroll
        for (int t = 0; t < 2; t++)
            af[t] = *(const bf16x8*)(As + (wm + t * 16 + l16) * 32 + quad * 8);
#pragma unroll
        for (int t = 0; t < 4; t++)
            bfr[t] = *(const bf16x8*)(Bs + (wn + t * 16 + l16) * 32 + quad * 8);
#pragma unroll
        for (int mt = 0; mt < 2; mt++)
#pragma unroll
            for (int nt = 0; nt < 4; nt++)
                acc[mt][nt] = mfma16(af[mt], bfr[nt], acc[mt][nt]);
    }

#pragma unroll
    for (int mt = 0; mt < 2; mt++)
#pragma unroll
        for (int nt = 0; nt < 4; nt++)
#pragma unroll
            for (int r = 0; r < 4; r++) {
                int gm = m0 + wm + mt * 16 + quad * 4 + r;
                int gn = n0 + wn + nt * 16 + l16;
                Cout[(size_t)gm * N + gn] = acc[mt][nt][r];
            }
}

// ---------------- attention (r5-exact + final vmcnt drain) ----------------
// measured 60-62 µs, MfmaUtil ~25%, VALUBusy ~44%.
__global__ __launch_bounds__(256, 2) void attn(
    const short* __restrict__ Q, const short* __restrict__ Kmat,
    const short* __restrict__ Vt, const float* __restrict__ btab,
    short* __restrict__ O) {
    __shared__ short Ks[2][64 * 64];
    __shared__ short Vs[2][64 * 64];
    __shared__ float bias_s[2176];
    __shared__ short P_s[4][2][16 * 64];

    int tid = threadIdx.x;
    int wave = tid >> 6, lane = tid & 63;
    int quad = lane >> 4, l16 = lane & 15;
    int bh = blockIdx.x;
    int h = bh & 15, b = bh >> 4;
    int q0b = blockIdx.y * 128;
    int q0w = q0b + wave * 32;

    const short* Qb = Q + (size_t)bh * SS * DKK;
    const short* Kb = Kmat + (size_t)bh * SS * DKK;
    const short* Vb = Vt + (size_t)bh * DKK * SS;
    const float* bt = btab + h * 4095;

    int woff = 1920 - q0b;
    for (int i = tid; i < 2176; i += 256) {
        int gi = woff + i;
        bias_s[i] = bt[gi > 4094 ? 4094 : gi];
    }
    float blo = bt[2047 - 128];
    float bhi = bt[2047 + 128];

    int kro = tid >> 3;
    int gk = (tid & 7) ^ (kro & 7);
    const short* Kg0 = Kb + (size_t)kro * DKK + gk * 8;
    const short* Kg1 = Kb + (size_t)(kro + 32) * DKK + gk * 8;
    const short* Vg0 = Vb + (size_t)kro * SS + gk * 8;
    const short* Vg1 = Vb + (size_t)(kro + 32) * SS + gk * 8;

    bf16x8 qf[2][2];
#pragma unroll
    for (int qs = 0; qs < 2; qs++) {
        qf[qs][0] = *(const bf16x8*)(Qb + (q0w + qs * 16 + l16) * DKK + quad * 8);
        qf[qs][1] = *(const bf16x8*)(Qb + (q0w + qs * 16 + l16) * DKK + 32 + quad * 8);
    }

    f32x4 o[2][4];
#pragma unroll
    for (int qs = 0; qs < 2; qs++)
#pragma unroll
        for (int i = 0; i < 4; i++) o[qs][i] = (f32x4){0.f, 0.f, 0.f, 0.f};
    f32x4 lacc[2];
    lacc[0] = (f32x4){0.f, 0.f, 0.f, 0.f};
    lacc[1] = (f32x4){0.f, 0.f, 0.f, 0.f};

    bf16x8 onesf;
    short onev = (l16 == 0) ? (short)0x3F80 : (short)0;
#pragma unroll
    for (int i = 0; i < 8; i++) onesf[i] = onev;

    short* Pw = &P_s[wave][0][0];
    int gxor = l16 & 7;
    int ghalf = quad >> 1;
    int wbase = l16 * 64 + (quad & 1) * 4;
    int ra0 = l16 * 64 + ((quad ^ gxor) * 8);
    int ra1 = l16 * 64 + (((4 + quad) ^ gxor) * 8);
    int bidx = 127 + quad * 4 - wave * 32 - l16;
    int sl0 = (quad ^ gxor) * 8;
    int sl1 = ((4 + quad) ^ gxor) * 8;

    lds16(Kg0, &Ks[0][wave * 512]);
    lds16(Kg1, &Ks[0][2048 + wave * 512]);
    lds16(Vg0, &Vs[0][wave * 512]);
    lds16(Vg1, &Vs[0][2048 + wave * 512]);

    int cur = 0;
    for (int kc = 0; kc < SS; kc += 64) {
        __syncthreads();
        int kn = (kc + 64) & (SS - 1);
        int nxt = cur ^ 1;
        lds16(Kg0 + (size_t)kn * DKK, &Ks[nxt][wave * 512]);
        lds16(Kg1 + (size_t)kn * DKK, &Ks[nxt][2048 + wave * 512]);
        lds16(Vg0 + kn, &Vs[nxt][wave * 512]);
        lds16(Vg1 + kn, &Vs[nxt][2048 + wave * 512]);

        float breg[2][16];
#pragma unroll
        for (int qs = 0; qs < 2; qs++) {
            int q0s = q0w + qs * 16;
            if (kc > q0s - 191 && kc < q0s + 143) {
#pragma unroll
                for (int kt = 0; kt < 4; kt++)
#pragma unroll
                    for (int r = 0; r < 4; r++)
                        breg[qs][kt * 4 + r] =
                            bias_s[bidx + kc + kt * 16 + r - qs * 16];
            } else {
                float bc = (kc <= q0s - 191) ? blo : bhi;
#pragma unroll
                for (int i = 0; i < 16; i++) breg[qs][i] = bc;
            }
        }

        const short* Ksc = &Ks[cur][0];
        const short* Vsc = &Vs[cur][0];

        f32x4 s[2][4];
#pragma unroll
        for (int kt = 0; kt < 4; kt++) {
            int row = (kt * 16 + l16) * 64;
            bf16x8 kf0 = *(const bf16x8*)(Ksc + row + sl0);
            bf16x8 kf1 = *(const bf16x8*)(Ksc + row + sl1);
            s[0][kt] = mfma16(kf0, qf[0][0], (f32x4){0.f, 0.f, 0.f, 0.f});
            s[0][kt] = mfma16(kf1, qf[0][1], s[0][kt]);
            s[1][kt] = mfma16(kf0, qf[1][0], (f32x4){0.f, 0.f, 0.f, 0.f});
            s[1][kt] = mfma16(kf1, qf[1][1], s[1][kt]);
        }
        bf16x8 vf[4][2];
#pragma unroll
        for (int nt = 0; nt < 4; nt++) {
            int row = (nt * 16 + l16) * 64;
            vf[nt][0] = *(const bf16x8*)(Vsc + row + sl0);
            vf[nt][1] = *(const bf16x8*)(Vsc + row + sl1);
        }

#pragma unroll
        for (int qs = 0; qs < 2; qs++) {
#pragma unroll
            for (int kt = 0; kt < 4; kt++) {
                unsigned u[4];
#pragma unroll
                for (int r = 0; r < 4; r++) {
                    float p = __builtin_amdgcn_exp2f(
                        fmaf(s[qs][kt][r], 1.44269504f, breg[qs][kt * 4 + r]));
                    u[r] = f2u(p) + 0x8000u;
                }
                unsigned d0 = __builtin_amdgcn_perm(u[1], u[0], 0x07060302u);
                unsigned d1 = __builtin_amdgcn_perm(u[3], u[2], 0x07060302u);
                int g = (kt * 2 + ghalf) ^ gxor;
                *(i32x2*)(Pw + qs * 1024 + wbase + g * 8) = (i32x2){(int)d0, (int)d1};
            }
        }
        __asm__ __volatile__("" ::: "memory");
#pragma unroll
        for (int qs = 0; qs < 2; qs++) {
            bf16x8 pf0 = *(const bf16x8*)(Pw + qs * 1024 + ra0);
            bf16x8 pf1 = *(const bf16x8*)(Pw + qs * 1024 + ra1);
            lacc[qs] = mfma16(pf0, onesf, lacc[qs]);
            lacc[qs] = mfma16(pf1, onesf, lacc[qs]);
#pragma unroll
            for (int nt = 0; nt < 4; nt++) {
                o[qs][nt] = mfma16(pf0, vf[nt][0], o[qs][nt]);
                o[qs][nt] = mfma16(pf1, vf[nt][1], o[qs][nt]);
            }
        }
        __asm__ __volatile__("" ::: "memory");
        cur ^= 1;
    }
    __builtin_amdgcn_s_waitcnt(WAITCNT_VM0); // wrapped DMAs land before retirement

#pragma unroll
    for (int qs = 0; qs < 2; qs++) {
        float inv[4];
#pragma unroll
        for (int r = 0; r < 4; r++) {
            float l = __shfl(lacc[qs][r], lane & 48);
            inv[r] = 1.f / l;
        }
#pragma unroll
        for (int nt = 0; nt < 4; nt++)
#pragma unroll
            for (int r = 0; r < 4; r++) {
                int qrow = q0w + qs * 16 + quad * 4 + r;
                int dk = nt * 16 + l16;
                O[((size_t)(b * SS + qrow)) * (HH * DKK) + h * DKK + dk] =
                    bf16b(o[qs][nt][r] * inv[r]);
            }
    }
}

extern "C" void kernel_launch(void* const* d_in, const int* in_sizes, int n_in,
                              void* d_out, int out_size, void* d_ws, size_t ws_size,
                              hipStream_t stream) {
    const float* hs = (const float*)d_in[0];
    const float* Wq = (const float*)d_in[1];
    const float* Wk = (const float*)d_in[2];
    const float* Wv = (const float*)d_in[3];
    const float* Wo = (const float*)d_in[4];
    const float* rb = (const float*)d_in[5];
    float* out = (float*)d_out;

    char* ws = (char*)d_ws;
    size_t off = 0;
    auto alloc = [&](size_t bytes) -> void* {
        void* p = (void*)(ws + off);
        off += (bytes + 255) & ~(size_t)255;
        return p;
    };
    const size_t M = (size_t)BB * SS; // 4096
    short* hsb = (short*)alloc(M * DD * 2);
    // WqT/WkT/WvT MUST stay contiguous (2MB each, 256-aligned -> no padding):
    // gemm_qkv reads them as one [3072][1024] matrix.
    short* WqT = (short*)alloc((size_t)DD * DD * 2);
    short* WkT = (short*)alloc((size_t)DD * DD * 2);
    short* WvT = (short*)alloc((size_t)DD * DD * 2);
    short* WoT = (short*)alloc((size_t)DD * DD * 2);
    short* Qb  = (short*)alloc(M * DD * 2);
    short* Kb  = (short*)alloc(M * DD * 2);
    short* VTb = (short*)alloc(M * DD * 2);
    short* Ab  = (short*)alloc(M * DD * 2);
    float* btab = (float*)alloc((size_t)HH * 4095 * 4);

    prep<<<8448, 256, 0, stream>>>(hs, Wq, Wk, Wv, Wo, rb,
                                   hsb, WqT, WkT, WvT, WoT, btab);
    gemm_qkv<<<dim3(24, 32), 256, 0, stream>>>(hsb, WqT, Qb, Kb, VTb);
    attn<<<dim3(32, 16), 256, 0, stream>>>(Qb, Kb, VTb, btab, Ab);
    gemm_out<<<dim3(8, 64), 256, 0, stream>>>(Ab, WoT, out);
}